// Round 5
// baseline (1103.054 us; speedup 1.0000x reference)
//
#include <hip/hip_runtime.h>
#include <hip/hip_fp16.h>

#define FIN 512
#define FMID 16
#define FOUT 64

// bucket = dst >> 5 : 32 nodes per bucket; record = (src<<5) | (dst&31)
#define BBITS 5
#define BSZ 32
#define NB_MAX 4096
#define NWG_SC 128
#define T_SC 512
#define REC_PAD 256

// ---------- bucket count: LDS histogram per wg, one global atomic per bucket ----------
__global__ __launch_bounds__(T_SC) void k_bcount(const int* __restrict__ dst,
                                                 int* __restrict__ bcnt,
                                                 int E, int nb, int chunk) {
  __shared__ int cnt[NB_MAX];
  const int t = threadIdx.x;
  for (int i = t; i < nb; i += T_SC) cnt[i] = 0;
  __syncthreads();
  const int beg = blockIdx.x * chunk;
  const int end = min(beg + chunk, E);
  const int n4 = (end - beg) >> 2;
  const int4* d4 = (const int4*)(dst + beg);
  for (int i = t; i < n4; i += T_SC) {
    int4 v = d4[i];
    atomicAdd(&cnt[v.x >> BBITS], 1);
    atomicAdd(&cnt[v.y >> BBITS], 1);
    atomicAdd(&cnt[v.z >> BBITS], 1);
    atomicAdd(&cnt[v.w >> BBITS], 1);
  }
  for (int e = beg + (n4 << 2) + t; e < end; e += T_SC) atomicAdd(&cnt[dst[e] >> BBITS], 1);
  __syncthreads();
  for (int i = t; i < nb; i += T_SC) {
    int c = cnt[i];
    if (c) atomicAdd(&bcnt[i], c);
  }
}

// ---------- exclusive scan of bcnt[nb] -> boff, bcur; also writes rec sentinel pad
// ---------- and zeroes the dummy source row N of hs/a1s ----------
__global__ __launch_bounds__(256) void k_bscan(const int* __restrict__ bcnt,
                                               int* __restrict__ boff,
                                               int* __restrict__ bcur, int nb,
                                               unsigned* __restrict__ rec, int E,
                                               __half* __restrict__ hs,
                                               __half* __restrict__ a1s, int N) {
  __shared__ int part[256];
  const int t = threadIdx.x;
  const int PER = 16;  // 256*16 = 4096 >= nb
  int v[PER], s = 0;
#pragma unroll
  for (int u = 0; u < PER; ++u) {
    int idx = t * PER + u;
    v[u] = (idx < nb) ? bcnt[idx] : 0;
    s += v[u];
  }
  part[t] = s;
  __syncthreads();
  for (int off = 1; off < 256; off <<= 1) {
    int x = (t >= off) ? part[t - off] : 0;
    __syncthreads();
    part[t] += x;
    __syncthreads();
  }
  int run = part[t] - s;
#pragma unroll
  for (int u = 0; u < PER; ++u) {
    int idx = t * PER + u;
    if (idx < nb) { boff[idx] = run; bcur[idx] = run; }
    run += v[u];
  }
  // sentinel pad: points at dummy src row N (zeros), dstlow 0 (adds 0.0 -> harmless)
  rec[E + t] = (unsigned)N << BBITS;
  if (t < FMID) {
    hs[(size_t)N * FMID + t] = __float2half(0.f);
    a1s[(size_t)N * FMID + t] = __float2half(0.f);
  }
}

// ---------- scatter: per-wg LDS hist -> claim contiguous runs -> ranked writes ----------
__global__ __launch_bounds__(T_SC) void k_bscatter(const int* __restrict__ src,
                                                   const int* __restrict__ dst,
                                                   int* __restrict__ bcur,
                                                   unsigned* __restrict__ rec,
                                                   int E, int nb, int chunk) {
  __shared__ int cnt[NB_MAX];
  __shared__ int goff[NB_MAX];
  const int t = threadIdx.x;
  for (int i = t; i < nb; i += T_SC) cnt[i] = 0;
  __syncthreads();
  const int beg = blockIdx.x * chunk;
  const int end = min(beg + chunk, E);
  const int n4 = (end - beg) >> 2;
  const int4* d4 = (const int4*)(dst + beg);
  const int4* s4 = (const int4*)(src + beg);
  for (int i = t; i < n4; i += T_SC) {
    int4 v = d4[i];
    atomicAdd(&cnt[v.x >> BBITS], 1);
    atomicAdd(&cnt[v.y >> BBITS], 1);
    atomicAdd(&cnt[v.z >> BBITS], 1);
    atomicAdd(&cnt[v.w >> BBITS], 1);
  }
  for (int e = beg + (n4 << 2) + t; e < end; e += T_SC) atomicAdd(&cnt[dst[e] >> BBITS], 1);
  __syncthreads();
  for (int i = t; i < nb; i += T_SC) {
    int c = cnt[i];
    goff[i] = c ? atomicAdd(&bcur[i], c) : 0;
  }
  __syncthreads();
  for (int i = t; i < nb; i += T_SC) cnt[i] = 0;
  __syncthreads();
  for (int i = t; i < n4; i += T_SC) {
    int4 dv = d4[i];
    int4 sv = s4[i];
#pragma unroll
    for (int u = 0; u < 4; ++u) {
      int d = (&dv.x)[u], s = (&sv.x)[u];
      int b = d >> BBITS;
      int r = atomicAdd(&cnt[b], 1);
      rec[goff[b] + r] = ((unsigned)s << BBITS) | (unsigned)(d & (BSZ - 1));
    }
  }
  for (int e = beg + (n4 << 2) + t; e < end; e += T_SC) {
    int d = dst[e];
    int b = d >> BBITS;
    int r = atomicAdd(&cnt[b], 1);
    rec[goff[b] + r] = ((unsigned)src[e] << BBITS) | (unsigned)(d & (BSZ - 1));
  }
}

// ---------- degrees -> dis from bucketed records (one wg per bucket) ----------
__global__ __launch_bounds__(256) void k_bdis(const unsigned* __restrict__ rec,
                                              const int* __restrict__ boff,
                                              const int* __restrict__ bcnt,
                                              float* __restrict__ dis, int N) {
  __shared__ int cnt[BSZ];
  const int t = threadIdx.x;
  const int b = blockIdx.x;
  if (t < BSZ) cnt[t] = 0;
  __syncthreads();
  const int beg = boff[b], end = beg + bcnt[b];
  for (int i = beg + t; i < end; i += 256) atomicAdd(&cnt[rec[i] & (BSZ - 1)], 1);
  __syncthreads();
  if (t < BSZ) {
    int node = b * BSZ + t;
    if (node < N) dis[node] = rsqrtf(1.0f + (float)cnt[t]);  // +1 self-loop
  }
}

// ---------- hs = (x @ W1) * dis[node], fp16; W1 wave-uniform scalar loads ----------
__global__ __launch_bounds__(256) void k_gemm1(const float* __restrict__ x,
                                               const float* __restrict__ W1,
                                               const float* __restrict__ dis,
                                               __half* __restrict__ hs, int n) {
  int node = blockIdx.x * 256 + threadIdx.x;
  if (node >= n) return;
  const float4* xr = (const float4*)(x + (size_t)node * FIN);
  float acc[FMID];
#pragma unroll
  for (int j = 0; j < FMID; ++j) acc[j] = 0.f;
  for (int k4 = 0; k4 < FIN / 4; ++k4) {
    float4 xv = xr[k4];
    const float* wr = W1 + k4 * 4 * FMID;  // uniform across lanes -> s_load
#pragma unroll
    for (int j = 0; j < FMID; ++j) acc[j] += xv.x * wr[j];
#pragma unroll
    for (int j = 0; j < FMID; ++j) acc[j] += xv.y * wr[FMID + j];
#pragma unroll
    for (int j = 0; j < FMID; ++j) acc[j] += xv.z * wr[2 * FMID + j];
#pragma unroll
    for (int j = 0; j < FMID; ++j) acc[j] += xv.w * wr[3 * FMID + j];
  }
  const float d = dis[node];
  __half tmp[FMID];
#pragma unroll
  for (int j = 0; j < FMID; ++j) tmp[j] = __float2half(acc[j] * d);
  uint4* hout = (uint4*)(hs + (size_t)node * FMID);  // 32B, aligned
  hout[0] = ((const uint4*)tmp)[0];
  hout[1] = ((const uint4*)tmp)[1];
}

// ---------- propagation: one wg per 32-node bucket, LDS fp32 tile ----------
// Each 16-lane group owns a contiguous slice; per chunk of 16 edges it does ONE
// coalesced rec load (rec[base+j]), broadcasts via shfl, and issues 16
// independent random row-loads back-to-back (deep MLP), then 16 LDS atomics.
__global__ __launch_bounds__(256, 4) void k_prop(const __half* __restrict__ in,
                                                 const unsigned* __restrict__ rec,
                                                 const int* __restrict__ boff,
                                                 const int* __restrict__ bcnt,
                                                 const float* __restrict__ dis,
                                                 const float* __restrict__ bias,
                                                 __half* __restrict__ out, int N, int mode) {
  __shared__ float acc[BSZ * FMID];  // 2 KB
  const int t = threadIdx.x;
  const int b = blockIdx.x;
  for (int i = t; i < BSZ * FMID; i += 256) acc[i] = 0.f;
  __syncthreads();
  const int g = t >> 4;        // 16 groups per wg
  const int j = t & 15;
  const int lane = t & 63;
  const int lbase = lane & 48; // first lane of this group within the wave
  const int beg = boff[b], cnt = bcnt[b];
  const int sl = (cnt + 15) >> 4;              // slice length per group
  const int s0 = beg + g * sl;
  const int s1 = min(beg + (g + 1) * sl, beg + cnt);
  const unsigned SENT = (unsigned)N << BBITS;  // dummy row N = zeros, dstlow 0

  for (int base = s0; base < s1; base += 16) {
    unsigned rj = rec[base + j];               // coalesced 64B per group (padded)
    rj = (base + j < s1) ? rj : SENT;
    unsigned rr[16];
    float vv[16];
#pragma unroll
    for (int u = 0; u < 16; ++u) {
      rr[u] = (unsigned)__shfl((int)rj, lbase + u, 64);
      vv[u] = __half2float(in[((size_t)(rr[u] >> BBITS) << 4) + j]);  // 16 loads in flight
    }
#pragma unroll
    for (int u = 0; u < 16; ++u)
      atomicAdd(&acc[((rr[u] & (BSZ - 1)) << 4) + j], vv[u]);
  }
  __syncthreads();
  // flush: contiguous, fused dis[dst]-scale + self-loop (+bias+relu, pre-scale)
  for (int idx = t; idx < BSZ * FMID; idx += 256) {
    int node = (b << BBITS) + (idx >> 4);
    if (node < N) {
      float dd = dis[node];
      float selfv = __half2float(in[((size_t)node << 4) + (idx & 15)]);
      float v = dd * (acc[idx] + selfv);
      if (mode) v = fmaxf(v + bias[idx & 15], 0.f) * dd;  // pre-scale for next layer
      out[((size_t)node << 4) + (idx & 15)] = __float2half(v);
    }
  }
}

// ---------- out = log_softmax(a2 @ W2 + b2) : one wave per node ----------
__global__ __launch_bounds__(256) void k_out(const __half* __restrict__ a2,
                                             const float* __restrict__ W2,
                                             const float* __restrict__ b2,
                                             float* __restrict__ out, int n) {
  __shared__ float w[FMID * FOUT];  // 4 KB
  for (int idx = threadIdx.x; idx < FMID * FOUT; idx += 256) w[idx] = W2[idx];
  __syncthreads();
  const int lane = threadIdx.x & 63;
  const int node = blockIdx.x * 4 + (threadIdx.x >> 6);
  if (node >= n) return;
  const __half* ar = a2 + ((size_t)node << 4);
  float o = b2[lane];
#pragma unroll
  for (int k = 0; k < FMID; ++k) o += __half2float(ar[k]) * w[k * FOUT + lane];
  float m = o;
#pragma unroll
  for (int off = 32; off >= 1; off >>= 1) m = fmaxf(m, __shfl_xor(m, off));
  float e = __expf(o - m);
  float s = e;
#pragma unroll
  for (int off = 32; off >= 1; off >>= 1) s += __shfl_xor(s, off);
  out[(size_t)node * FOUT + lane] = o - m - __logf(s);
}

// ---------- launch ----------
extern "C" void kernel_launch(void* const* d_in, const int* in_sizes, int n_in,
                              void* d_out, int out_size, void* d_ws, size_t ws_size,
                              hipStream_t stream) {
  const float* x  = (const float*)d_in[0];
  const int* edge = (const int*)d_in[1];
  const float* W1 = (const float*)d_in[2];
  const float* b1 = (const float*)d_in[3];
  const float* W2 = (const float*)d_in[4];
  const float* b2 = (const float*)d_in[5];
  float* out = (float*)d_out;

  const int N = in_sizes[0] / FIN;  // 100000
  const int E = in_sizes[1] / 2;    // 3200000
  const int* src = edge;
  const int* dst = edge + E;

  const int NB = (N + BSZ - 1) / BSZ;  // 3125
  const int NA = (N + 63) & ~63;       // 100032 > N, so row N exists

  // ws layout (4-byte words):
  // bcnt[NB_MAX] | boff[NB_MAX] | bcur[NB_MAX] | dis[NA] | rec[E+pad] | hs | a1s | a2 (fp16, 16*NA each)
  int*      bcnt = (int*)d_ws;
  int*      boff = bcnt + NB_MAX;
  int*      bcur = boff + NB_MAX;
  float*    dis  = (float*)(bcur + NB_MAX);
  unsigned* rec  = (unsigned*)(dis + NA);
  __half*   hs   = (__half*)(rec + E + REC_PAD);
  __half*   a1s  = hs + (size_t)16 * NA;
  __half*   a2   = a1s + (size_t)16 * NA;

  const int T = 256;
  const int chunk = (E + NWG_SC - 1) / NWG_SC;

  hipMemsetAsync(bcnt, 0, NB * sizeof(int), stream);
  k_bcount  <<<NWG_SC, T_SC, 0, stream>>>(dst, bcnt, E, NB, chunk);
  k_bscan   <<<1, T, 0, stream>>>(bcnt, boff, bcur, NB, rec, E, hs, a1s, N);
  k_bscatter<<<NWG_SC, T_SC, 0, stream>>>(src, dst, bcur, rec, E, NB, chunk);
  k_bdis    <<<NB, T, 0, stream>>>(rec, boff, bcnt, dis, N);

  // hs = (x @ W1) * dis  (fp16, 3.2 MB)
  k_gemm1<<<(N + T - 1) / T, T, 0, stream>>>(x, W1, dis, hs, N);

  // layer 1: a1s = relu(P_hat hs + b1) * dis   (pre-scaled for layer 2)
  k_prop<<<NB, T, 0, stream>>>(hs, rec, boff, bcnt, dis, b1, a1s, N, 1);
  // layer 2: a2 = P_hat a1s
  k_prop<<<NB, T, 0, stream>>>(a1s, rec, boff, bcnt, dis, nullptr, a2, N, 0);

  // out = log_softmax(a2 @ W2 + b2)
  k_out<<<(N + 3) / 4, T, 0, stream>>>(a2, W2, b2, out, N);
}